// Round 1
// baseline (1352.614 us; speedup 1.0000x reference)
//
#include <hip/hip_runtime.h>
#include <math.h>
#include <stdint.h>

#define SEQ 4096
#define DIM 1024
#define NB  4

typedef __attribute__((ext_vector_type(8))) __bf16 bf16x8;
typedef __attribute__((ext_vector_type(4))) float  f32x4;
typedef __attribute__((ext_vector_type(4))) float  floatx4;
typedef __attribute__((ext_vector_type(8))) unsigned short ushortx8;
typedef __attribute__((ext_vector_type(4))) unsigned short ushortx4;

__device__ __forceinline__ unsigned short f2bf(float f){
  union { float f; unsigned int u; } c; c.f = f;
  unsigned int u = c.u;
  return (unsigned short)((u + 0x7fffu + ((u >> 16) & 1u)) >> 16);
}

__device__ __forceinline__ f32x4 mfma16(bf16x8 a, bf16x8 b, f32x4 c){
  return __builtin_amdgcn_mfma_f32_16x16x32_bf16(a, b, c, 0, 0, 0);
}

__device__ __forceinline__ void g2l16(void* lds, const void* g){
  __builtin_amdgcn_global_load_lds(
      (const __attribute__((address_space(1))) unsigned int*)g,
      (__attribute__((address_space(3))) unsigned int*)lds, 16, 0, 0);
}

// ---------------- fp32 -> bf16 conversion ----------------
__global__ void cvt_kernel(const float* __restrict__ src,
                           unsigned short* __restrict__ dst, int n4){
  int i = blockIdx.x * blockDim.x + threadIdx.x;
  if (i >= n4) return;
  floatx4 v = *((const floatx4*)src + i);
  ushortx4 o;
  o[0] = f2bf(v[0]); o[1] = f2bf(v[1]); o[2] = f2bf(v[2]); o[3] = f2bf(v[3]);
  *((ushortx4*)dst + i) = o;
}

// ---------------- QKV projection GEMM (m97 structure) ----------------
// C[m][n] = sum_k E[m][k] * W[n][k];  E:[16384][1024], W:[1024][1024]
__global__ __launch_bounds__(256, 2) void gemm_qkv(
    const unsigned short* __restrict__ E,
    const unsigned short* __restrict__ W3,
    unsigned short* __restrict__ Qd,
    unsigned short* __restrict__ Kd,
    unsigned short* __restrict__ Vd)
{
  __shared__ unsigned short As[128][64];
  __shared__ unsigned short Bs[128][64];

  const int t  = threadIdx.x;
  const int m0 = blockIdx.y * 128;
  const int n0 = blockIdx.x * 128;
  const unsigned short* W = W3 + (size_t)blockIdx.z * (DIM * (size_t)DIM);
  unsigned short* dst = blockIdx.z == 0 ? Qd : (blockIdx.z == 1 ? Kd : Vd);

  const int l  = t & 63;
  const int w  = t >> 6;
  const int lr = l & 15;
  const int lk = l >> 4;
  const int wr = (w >> 1) * 64;
  const int wc = (w & 1) * 64;

  f32x4 acc[4][4];
  #pragma unroll
  for (int i = 0; i < 4; ++i)
    #pragma unroll
    for (int j = 0; j < 4; ++j) acc[i][j] = (f32x4)0.0f;

  for (int kt = 0; kt < DIM / 64; ++kt){
    const int k0 = kt * 64;
    #pragma unroll
    for (int c = 0; c < 4; ++c){
      int id  = c * 256 + t;
      int row = id >> 3;
      int cb  = (id & 7) * 8;
      g2l16(&As[row][cb], E + (size_t)(m0 + row) * DIM + k0 + cb);
      g2l16(&Bs[row][cb], W + (size_t)(n0 + row) * DIM + k0 + cb);
    }
    asm volatile("s_waitcnt vmcnt(0)" ::: "memory");
    __syncthreads();
    #pragma unroll
    for (int ks = 0; ks < 2; ++ks){
      bf16x8 af[4], bfr[4];
      #pragma unroll
      for (int i = 0; i < 4; ++i){
        af[i]  = *(const bf16x8*)&As[wr + i*16 + lr][ks*32 + lk*8];
        bfr[i] = *(const bf16x8*)&Bs[wc + i*16 + lr][ks*32 + lk*8];
      }
      #pragma unroll
      for (int i = 0; i < 4; ++i)
        #pragma unroll
        for (int j = 0; j < 4; ++j)
          acc[i][j] = mfma16(af[i], bfr[j], acc[i][j]);
    }
    __syncthreads();
  }
  #pragma unroll
  for (int i = 0; i < 4; ++i)
    #pragma unroll
    for (int j = 0; j < 4; ++j)
      #pragma unroll
      for (int r = 0; r < 4; ++r){
        int row = wr + i*16 + lk*4 + r;
        int col = wc + j*16 + lr;
        dst[(size_t)(m0 + row) * DIM + n0 + col] = f2bf(acc[i][j][r]);
      }
}

// ---------------- V transpose: VT[b][a][s] = V[b][s][a] ----------------
__global__ __launch_bounds__(256) void transpose_v(
    const unsigned short* __restrict__ V, unsigned short* __restrict__ VT)
{
  __shared__ unsigned short T[64][72];
  const int b  = blockIdx.z;
  const int s0 = blockIdx.x * 64;
  const int a0 = blockIdx.y * 64;
  const unsigned short* Vb = V + (size_t)b * SEQ * DIM;
  unsigned short* VTb = VT + (size_t)b * DIM * SEQ;
  const int t = threadIdx.x;
  const int r = t >> 3, cg = t & 7;
  #pragma unroll
  for (int p = 0; p < 2; ++p){
    int row = r + p * 32;
    ushortx8 v = *(const ushortx8*)(Vb + (size_t)(s0 + row) * DIM + a0 + cg*8);
    *(ushortx8*)&T[row][cg*8] = v;
  }
  __syncthreads();
  #pragma unroll
  for (int p = 0; p < 2; ++p){
    int ar = r + p * 32;
    ushortx8 o;
    #pragma unroll
    for (int j = 0; j < 8; ++j) o[j] = T[cg*8 + j][ar];
    *(ushortx8*)(VTb + (size_t)(a0 + ar) * SEQ + s0 + cg*8) = o;
  }
}

// ---------------- flash attention ----------------
// grid (64 qtiles, 4 batches), block 512 (8 waves). BQ=64, BK=64.
// Q tile in LDS (XOR-swizzled). K, VT fragments direct from global (L2).
__global__ __launch_bounds__(512, 2) void flash_attn(
    const unsigned short* __restrict__ Q,
    const unsigned short* __restrict__ K,
    const unsigned short* __restrict__ VT,
    float* __restrict__ out)
{
  __shared__ unsigned short Qs[64 * 1024];   // 128 KB, swizzled
  __shared__ float Ss[64][68];               // 17 KB
  __shared__ unsigned short Ps[64][72];      // 9 KB
  __shared__ float mS[64], lS[64], aS[64];

  const int qt = blockIdx.x;
  const int b  = blockIdx.y;
  const int t  = threadIdx.x;
  const int w  = t >> 6;
  const int l  = t & 63;
  const int lr = l & 15;
  const int lk = l >> 4;

  const unsigned short* Qg = Q + ((size_t)b * SEQ + (size_t)qt * 64) * DIM;
  char* QsB = (char*)Qs;

  // stage Q tile: linear LDS dest, pre-swizzled global source (rule #21)
  #pragma unroll
  for (int c = 0; c < 16; ++c){
    int id  = c * 512 + t;            // 0..8191 chunks of 16B
    int row = id >> 7;                // 64 rows x 2048B
    int cB  = (id & 127) * 16;
    int sB  = cB ^ ((row & 7) << 4);
    g2l16(QsB + (size_t)id * 16, (const char*)Qg + (size_t)row * 2048 + sB);
  }
  if (t < 64){ mS[t] = -INFINITY; lS[t] = 0.0f; }

  f32x4 acc[4][8];
  #pragma unroll
  for (int i = 0; i < 4; ++i)
    #pragma unroll
    for (int n = 0; n < 8; ++n) acc[i][n] = (f32x4)0.0f;

  asm volatile("s_waitcnt vmcnt(0)" ::: "memory");
  __syncthreads();

  const float scale = 0.03125f;  // 1/sqrt(1024)
  const int mf  = w >> 1;
  const int nfb = (w & 1) * 2;

  for (int j = 0; j <= qt; ++j){
    const unsigned short* Kg = K + ((size_t)b * SEQ + (size_t)j * 64) * DIM;

    // ---- phase A: S = Q K^T (each wave: 2 frags sharing M-rows) ----
    f32x4 sa0 = (f32x4)0.0f, sa1 = (f32x4)0.0f;
    {
      const int arow = mf * 16 + lr;
      const char* aRow = QsB + (size_t)arow * 2048;
      const int aswz = (arow & 7) << 4;
      const unsigned short* kg0 = Kg + (size_t)(nfb * 16 + lr) * DIM + lk * 8;
      const unsigned short* kg1 = kg0 + 16 * DIM;
      #pragma unroll 4
      for (int ks = 0; ks < 32; ++ks){
        bf16x8 a  = *(const bf16x8*)(aRow + ((ks * 64 + lk * 16) ^ aswz));
        bf16x8 b0 = *(const bf16x8*)(kg0 + ks * 32);
        bf16x8 b1 = *(const bf16x8*)(kg1 + ks * 32);
        sa0 = mfma16(a, b0, sa0);
        sa1 = mfma16(a, b1, sa1);
      }
    }
    #pragma unroll
    for (int r = 0; r < 4; ++r){
      int row = mf * 16 + lk * 4 + r;
      Ss[row][nfb * 16 + lr]       = sa0[r];
      Ss[row][(nfb + 1) * 16 + lr] = sa1[r];
    }
    __syncthreads();

    // ---- phase B: online softmax over this 64x64 tile ----
    {
      const int row = t >> 3, cg = t & 7;
      f32x4 v0 = *(const f32x4*)&Ss[row][cg * 8];
      f32x4 v1 = *(const f32x4*)&Ss[row][cg * 8 + 4];
      const int grow = qt * 64 + row;
      const int gc0  = j * 64 + cg * 8;
      float sv[8];
      #pragma unroll
      for (int i2 = 0; i2 < 4; ++i2){
        sv[i2]     = (gc0 + i2     > grow) ? -INFINITY : v0[i2] * scale;
        sv[i2 + 4] = (gc0 + i2 + 4 > grow) ? -INFINITY : v1[i2] * scale;
      }
      float mx = sv[0];
      #pragma unroll
      for (int i2 = 1; i2 < 8; ++i2) mx = fmaxf(mx, sv[i2]);
      #pragma unroll
      for (int d = 1; d < 8; d <<= 1) mx = fmaxf(mx, __shfl_xor(mx, d, 64));
      float mprev = mS[row];
      float mnew  = fmaxf(mprev, mx);
      float alpha = __expf(mprev - mnew);
      float sum = 0.f;
      ushortx8 pb;
      #pragma unroll
      for (int i2 = 0; i2 < 8; ++i2){
        float p = __expf(sv[i2] - mnew);
        sum += p;
        pb[i2] = f2bf(p);
      }
      #pragma unroll
      for (int d = 1; d < 8; d <<= 1) sum += __shfl_xor(sum, d, 64);
      if (cg == 0){
        mS[row] = mnew;
        lS[row] = lS[row] * alpha + sum;
        aS[row] = alpha;
      }
      *(ushortx8*)&Ps[row][cg * 8] = pb;
    }
    __syncthreads();

    // ---- phase C: O = O*alpha + P * V  (wave w owns d-cols [w*128, w*128+128)) ----
    const unsigned short* Vg = VT + (size_t)b * DIM * SEQ
                                  + (size_t)(w * 128) * SEQ + (size_t)j * 64;
    #pragma unroll
    for (int i = 0; i < 4; ++i)
      #pragma unroll
      for (int r = 0; r < 4; ++r){
        float al = aS[i * 16 + lk * 4 + r];
        #pragma unroll
        for (int n = 0; n < 8; ++n) acc[i][n][r] *= al;
      }
    #pragma unroll
    for (int ks = 0; ks < 2; ++ks){
      bf16x8 pa[4];
      #pragma unroll
      for (int i = 0; i < 4; ++i)
        pa[i] = *(const bf16x8*)&Ps[i * 16 + lr][ks * 32 + lk * 8];
      #pragma unroll
      for (int n = 0; n < 8; ++n){
        bf16x8 vb = *(const bf16x8*)(Vg + (size_t)(n * 16 + lr) * SEQ + ks * 32 + lk * 8);
        #pragma unroll
        for (int i = 0; i < 4; ++i)
          acc[i][n] = mfma16(pa[i], vb, acc[i][n]);
      }
    }
  }

  // ---- epilogue: O / l ----
  float* ob = out + ((size_t)b * SEQ + (size_t)qt * 64) * DIM + w * 128;
  #pragma unroll
  for (int i = 0; i < 4; ++i)
    #pragma unroll
    for (int r = 0; r < 4; ++r){
      int row = i * 16 + lk * 4 + r;
      float inv = 1.0f / lS[row];
      #pragma unroll
      for (int n = 0; n < 8; ++n)
        ob[(size_t)row * DIM + n * 16 + lr] = acc[i][n][r] * inv;
    }
}

// ---------------- launch ----------------
extern "C" void kernel_launch(void* const* d_in, const int* in_sizes, int n_in,
                              void* d_out, int out_size, void* d_ws, size_t ws_size,
                              hipStream_t stream)
{
  (void)in_sizes; (void)n_in; (void)out_size; (void)ws_size;
  const float* emb = (const float*)d_in[0];
  const float* Wq  = (const float*)d_in[1];
  const float* Wk  = (const float*)d_in[2];
  const float* Wv  = (const float*)d_in[3];

  char* ws = (char*)d_ws;
  unsigned short* EB = (unsigned short*)ws;                    // 32MB (later reused as VT)
  unsigned short* WB = (unsigned short*)(ws + 33554432);       // 6MB: Wq|Wk|Wv bf16
  unsigned short* Qb = (unsigned short*)(ws + 39845888);       // 32MB
  unsigned short* Kb = (unsigned short*)(ws + 73400320);       // 32MB
  unsigned short* Vb = (unsigned short*)d_out;                 // V scratch in out buffer
  unsigned short* VT = EB;                                     // alias: E dead after gemm

  cvt_kernel<<<16384, 256, 0, stream>>>(emb, EB, 4194304);
  cvt_kernel<<<1024, 256, 0, stream>>>(Wq, WB,           262144);
  cvt_kernel<<<1024, 256, 0, stream>>>(Wk, WB + 1048576, 262144);
  cvt_kernel<<<1024, 256, 0, stream>>>(Wv, WB + 2097152, 262144);

  gemm_qkv<<<dim3(8, 128, 3), 256, 0, stream>>>(EB, WB, Qb, Kb, Vb);
  transpose_v<<<dim3(64, 16, 4), 256, 0, stream>>>(Vb, VT);
  flash_attn<<<dim3(64, 4), 512, 0, stream>>>(Qb, Kb, VT, (float*)d_out);
}

// Round 2
// 1150.727 us; speedup vs baseline: 1.1754x; 1.1754x over previous
//
#include <hip/hip_runtime.h>
#include <math.h>
#include <stdint.h>

#define SEQ 4096
#define DIM 1024
#define NB  4

typedef __attribute__((ext_vector_type(8))) __bf16 bf16x8;
typedef __attribute__((ext_vector_type(4))) float  f32x4;
typedef __attribute__((ext_vector_type(4))) float  floatx4;
typedef __attribute__((ext_vector_type(8))) unsigned short ushortx8;
typedef __attribute__((ext_vector_type(4))) unsigned short ushortx4;

__device__ __forceinline__ unsigned short f2bf(float f){
  union { float f; unsigned int u; } c; c.f = f;
  unsigned int u = c.u;
  return (unsigned short)((u + 0x7fffu + ((u >> 16) & 1u)) >> 16);
}

__device__ __forceinline__ f32x4 mfma16(bf16x8 a, bf16x8 b, f32x4 c){
  return __builtin_amdgcn_mfma_f32_16x16x32_bf16(a, b, c, 0, 0, 0);
}

__device__ __forceinline__ void g2l16(void* lds, const void* g){
  __builtin_amdgcn_global_load_lds(
      (const __attribute__((address_space(1))) unsigned int*)g,
      (__attribute__((address_space(3))) unsigned int*)lds, 16, 0, 0);
}

// ---------------- fp32 -> bf16 conversion ----------------
__global__ void cvt_kernel(const float* __restrict__ src,
                           unsigned short* __restrict__ dst, int n4){
  int i = blockIdx.x * blockDim.x + threadIdx.x;
  if (i >= n4) return;
  floatx4 v = *((const floatx4*)src + i);
  ushortx4 o;
  o[0] = f2bf(v[0]); o[1] = f2bf(v[1]); o[2] = f2bf(v[2]); o[3] = f2bf(v[3]);
  *((ushortx4*)dst + i) = o;
}

// ---------------- QKV projection GEMM (m97 structure) ----------------
__global__ __launch_bounds__(256, 2) void gemm_qkv(
    const unsigned short* __restrict__ E,
    const unsigned short* __restrict__ W3,
    unsigned short* __restrict__ Qd,
    unsigned short* __restrict__ Kd,
    unsigned short* __restrict__ Vd)
{
  __shared__ unsigned short As[128][64];
  __shared__ unsigned short Bs[128][64];

  const int t  = threadIdx.x;
  const int m0 = blockIdx.y * 128;
  const int n0 = blockIdx.x * 128;
  const unsigned short* W = W3 + (size_t)blockIdx.z * (DIM * (size_t)DIM);
  unsigned short* dst = blockIdx.z == 0 ? Qd : (blockIdx.z == 1 ? Kd : Vd);

  const int l  = t & 63;
  const int w  = t >> 6;
  const int lr = l & 15;
  const int lk = l >> 4;
  const int wr = (w >> 1) * 64;
  const int wc = (w & 1) * 64;

  f32x4 acc[4][4];
  #pragma unroll
  for (int i = 0; i < 4; ++i)
    #pragma unroll
    for (int j = 0; j < 4; ++j) acc[i][j] = (f32x4)0.0f;

  for (int kt = 0; kt < DIM / 64; ++kt){
    const int k0 = kt * 64;
    #pragma unroll
    for (int c = 0; c < 4; ++c){
      int id  = c * 256 + t;
      int row = id >> 3;
      int cb  = (id & 7) * 8;
      g2l16(&As[row][cb], E + (size_t)(m0 + row) * DIM + k0 + cb);
      g2l16(&Bs[row][cb], W + (size_t)(n0 + row) * DIM + k0 + cb);
    }
    asm volatile("s_waitcnt vmcnt(0)" ::: "memory");
    __syncthreads();
    #pragma unroll
    for (int ks = 0; ks < 2; ++ks){
      bf16x8 af[4], bfr[4];
      #pragma unroll
      for (int i = 0; i < 4; ++i){
        af[i]  = *(const bf16x8*)&As[wr + i*16 + lr][ks*32 + lk*8];
        bfr[i] = *(const bf16x8*)&Bs[wc + i*16 + lr][ks*32 + lk*8];
      }
      #pragma unroll
      for (int i = 0; i < 4; ++i)
        #pragma unroll
        for (int j = 0; j < 4; ++j)
          acc[i][j] = mfma16(af[i], bfr[j], acc[i][j]);
    }
    __syncthreads();
  }
  #pragma unroll
  for (int i = 0; i < 4; ++i)
    #pragma unroll
    for (int j = 0; j < 4; ++j)
      #pragma unroll
      for (int r = 0; r < 4; ++r){
        int row = wr + i*16 + lk*4 + r;
        int col = wc + j*16 + lr;
        dst[(size_t)(m0 + row) * DIM + n0 + col] = f2bf(acc[i][j][r]);
      }
}

// ---------------- V transpose ----------------
__global__ __launch_bounds__(256) void transpose_v(
    const unsigned short* __restrict__ V, unsigned short* __restrict__ VT)
{
  __shared__ unsigned short T[64][72];
  const int b  = blockIdx.z;
  const int s0 = blockIdx.x * 64;
  const int a0 = blockIdx.y * 64;
  const unsigned short* Vb = V + (size_t)b * SEQ * DIM;
  unsigned short* VTb = VT + (size_t)b * DIM * SEQ;
  const int t = threadIdx.x;
  const int r = t >> 3, cg = t & 7;
  #pragma unroll
  for (int p = 0; p < 2; ++p){
    int row = r + p * 32;
    ushortx8 v = *(const ushortx8*)(Vb + (size_t)(s0 + row) * DIM + a0 + cg*8);
    *(ushortx8*)&T[row][cg*8] = v;
  }
  __syncthreads();
  #pragma unroll
  for (int p = 0; p < 2; ++p){
    int ar = r + p * 32;
    ushortx8 o;
    #pragma unroll
    for (int j = 0; j < 8; ++j) o[j] = T[cg*8 + j][ar];
    *(ushortx8*)(VTb + (size_t)(a0 + ar) * SEQ + s0 + cg*8) = o;
  }
}

// ---------------- flash attention v2 ----------------
// BQ=32, BK=64. grid (64 pairs, 4 batches) = 256 blocks, 512 threads (8 waves).
// Each block processes Q tiles (127-pair) then (pair): exactly 65 KV iters.
// Q tile in LDS (swizzled). K, VT fragments from global with 2-deep
// register double-buffer (16 loads in flight per wave).
__global__ __launch_bounds__(512, 2) void flash_attn(
    const unsigned short* __restrict__ Q,
    const unsigned short* __restrict__ K,
    const unsigned short* __restrict__ VT,
    float* __restrict__ out)
{
  __shared__ unsigned short Qs[32 * 1024];   // 64 KB, swizzled
  __shared__ float Ss[32][68];               // 8.7 KB
  __shared__ unsigned short Ps[32][80];      // 5 KB
  __shared__ float mS[32], lS[32], aS[32];

  const int pair = blockIdx.x;
  const int b    = blockIdx.y;
  const int t    = threadIdx.x;
  const int w    = t >> 6;
  const int l    = t & 63;
  const int lr   = l & 15;
  const int lk   = l >> 4;

  char* QsB = (char*)Qs;
  const float scale = 0.03125f;  // 1/sqrt(1024)

  // phase A wave roles: S[32x64] = 2M x 4N frags, one per wave
  const int mfa = w >> 2;
  const int nfa = w & 3;
  // phase C wave roles: O[32x1024]: rows mfc*16, d-range dr*256
  const int mfc = w & 1;
  const int dr  = w >> 1;

  for (int tix = 0; tix < 2; ++tix){
    const int qt = (tix == 0) ? (127 - pair) : pair;
    if (tix) __syncthreads();   // protect lS/Qs from previous tile

    if (t < 32){ mS[t] = -INFINITY; lS[t] = 0.0f; }

    // stage Q tile (pre-swizzled source, linear LDS dest)
    const unsigned short* Qg = Q + ((size_t)b * SEQ + (size_t)qt * 32) * DIM;
    #pragma unroll
    for (int c = 0; c < 8; ++c){
      int id  = c * 512 + t;            // 0..4095 chunks of 16B
      int row = id >> 7;                // 32 rows x 2048B
      int cB  = (id & 127) * 16;
      int sB  = cB ^ ((row & 7) << 4);
      g2l16(QsB + (size_t)id * 16, (const char*)Qg + (size_t)row * 2048 + sB);
    }

    f32x4 acc[16];
    #pragma unroll
    for (int n = 0; n < 16; ++n) acc[n] = (f32x4)0.0f;

    asm volatile("s_waitcnt vmcnt(0)" ::: "memory");
    __syncthreads();

    const int nj = qt / 2 + 1;
    for (int j = 0; j < nj; ++j){
      // ---- phase A: S = Q K^T, 2-deep pipelined register staging ----
      {
        const char* aRow = QsB + (size_t)(mfa * 16 + lr) * 2048;
        const int aswz = ((mfa * 16 + lr) & 7) << 4;
        const unsigned short* kg =
            K + ((size_t)b * SEQ + (size_t)j * 64 + nfa * 16 + lr) * DIM + lk * 8;

        f32x4 s0 = (f32x4)0.0f, s1 = (f32x4)0.0f;
        bf16x8 aR0[8], bR0[8], aR1[8], bR1[8];
        #pragma unroll
        for (int u = 0; u < 8; ++u){
          aR0[u] = *(const bf16x8*)(aRow + ((u * 64 + lk * 16) ^ aswz));
          bR0[u] = *(const bf16x8*)(kg + u * 32);
        }
        #pragma unroll
        for (int kb = 0; kb < 4; ++kb){
          bf16x8* curA = (kb & 1) ? aR1 : aR0;
          bf16x8* curB = (kb & 1) ? bR1 : bR0;
          bf16x8* nxtA = (kb & 1) ? aR0 : aR1;
          bf16x8* nxtB = (kb & 1) ? bR0 : bR1;
          if (kb < 3){
            #pragma unroll
            for (int u = 0; u < 8; ++u){
              int ks = (kb + 1) * 8 + u;
              nxtA[u] = *(const bf16x8*)(aRow + ((ks * 64 + lk * 16) ^ aswz));
              nxtB[u] = *(const bf16x8*)(kg + ks * 32);
            }
          }
          #pragma unroll
          for (int u = 0; u < 8; ++u){
            if (u & 1) s1 = mfma16(curA[u], curB[u], s1);
            else       s0 = mfma16(curA[u], curB[u], s0);
          }
        }
        s0 += s1;
        #pragma unroll
        for (int r = 0; r < 4; ++r)
          Ss[mfa * 16 + lk * 4 + r][nfa * 16 + lr] = s0[r];
      }
      __syncthreads();

      // ---- phase B: online softmax (16 lanes per row) ----
      {
        const int row = t >> 4;
        const int cg  = t & 15;
        f32x4 v0 = *(const f32x4*)&Ss[row][cg * 4];
        const int grow = qt * 32 + row;
        const int gc0  = j * 64 + cg * 4;
        float sv[4];
        #pragma unroll
        for (int i2 = 0; i2 < 4; ++i2)
          sv[i2] = (gc0 + i2 > grow) ? -INFINITY : v0[i2] * scale;
        float mx = fmaxf(fmaxf(sv[0], sv[1]), fmaxf(sv[2], sv[3]));
        #pragma unroll
        for (int d = 1; d < 16; d <<= 1) mx = fmaxf(mx, __shfl_xor(mx, d, 64));
        float mprev = mS[row];
        float mnew  = fmaxf(mprev, mx);
        float alpha = __expf(mprev - mnew);
        float sum = 0.f;
        ushortx4 pb;
        #pragma unroll
        for (int i2 = 0; i2 < 4; ++i2){
          float p = __expf(sv[i2] - mnew);
          sum += p;
          pb[i2] = f2bf(p);
        }
        #pragma unroll
        for (int d = 1; d < 16; d <<= 1) sum += __shfl_xor(sum, d, 64);
        if (cg == 0){
          mS[row] = mnew;
          lS[row] = lS[row] * alpha + sum;
          aS[row] = alpha;
        }
        *(ushortx4*)&Ps[row][cg * 4] = pb;
      }
      __syncthreads();

      // ---- phase C: O = O*alpha + P*V, 2-deep pipelined V staging ----
      {
        float al[4];
        #pragma unroll
        for (int r = 0; r < 4; ++r) al[r] = aS[mfc * 16 + lk * 4 + r];
        #pragma unroll
        for (int n = 0; n < 16; ++n)
          #pragma unroll
          for (int r = 0; r < 4; ++r) acc[n][r] *= al[r];

        bf16x8 pa0 = *(const bf16x8*)&Ps[mfc * 16 + lr][lk * 8];
        bf16x8 pa1 = *(const bf16x8*)&Ps[mfc * 16 + lr][32 + lk * 8];
        const unsigned short* vg = VT + (size_t)b * DIM * SEQ
                                      + (size_t)(dr * 256 + lr) * SEQ
                                      + (size_t)j * 64 + lk * 8;
        bf16x8 vR0[8], vR1[8];
        #pragma unroll
        for (int u = 0; u < 8; ++u)
          vR0[u] = *(const bf16x8*)(vg + (size_t)(u * 16) * SEQ);
        #pragma unroll
        for (int bb = 0; bb < 4; ++bb){
          bf16x8* cur = (bb & 1) ? vR1 : vR0;
          bf16x8* nxt = (bb & 1) ? vR0 : vR1;
          if (bb < 3){
            const int ks2 = (bb + 1) >> 1, nh2 = ((bb + 1) & 1) * 8;
            #pragma unroll
            for (int u = 0; u < 8; ++u)
              nxt[u] = *(const bf16x8*)(vg + (size_t)((nh2 + u) * 16) * SEQ + ks2 * 32);
          }
          const int ks = bb >> 1, nh = (bb & 1) * 8;
          bf16x8 pa = ks ? pa1 : pa0;
          #pragma unroll
          for (int u = 0; u < 8; ++u)
            acc[nh + u] = mfma16(pa, cur[u], acc[nh + u]);
        }
      }
    }

    // ---- epilogue: O / l ----
    {
      float* ob = out + ((size_t)b * SEQ + (size_t)qt * 32 + mfc * 16) * DIM + dr * 256;
      #pragma unroll
      for (int r = 0; r < 4; ++r){
        int rl = lk * 4 + r;
        float inv = 1.0f / lS[mfc * 16 + rl];
        #pragma unroll
        for (int n = 0; n < 16; ++n)
          ob[(size_t)rl * DIM + n * 16 + lr] = acc[n][r] * inv;
      }
    }
  }
}

// ---------------- launch ----------------
extern "C" void kernel_launch(void* const* d_in, const int* in_sizes, int n_in,
                              void* d_out, int out_size, void* d_ws, size_t ws_size,
                              hipStream_t stream)
{
  (void)in_sizes; (void)n_in; (void)out_size; (void)ws_size;
  const float* emb = (const float*)d_in[0];
  const float* Wq  = (const float*)d_in[1];
  const float* Wk  = (const float*)d_in[2];
  const float* Wv  = (const float*)d_in[3];

  char* ws = (char*)d_ws;
  unsigned short* EB = (unsigned short*)ws;                    // 32MB (later reused as VT)
  unsigned short* WB = (unsigned short*)(ws + 33554432);       // 6MB
  unsigned short* Qb = (unsigned short*)(ws + 39845888);       // 32MB
  unsigned short* Kb = (unsigned short*)(ws + 73400320);       // 32MB
  unsigned short* Vb = (unsigned short*)d_out;                 // V scratch in out buffer
  unsigned short* VT = EB;

  cvt_kernel<<<16384, 256, 0, stream>>>(emb, EB, 4194304);
  cvt_kernel<<<1024, 256, 0, stream>>>(Wq, WB,           262144);
  cvt_kernel<<<1024, 256, 0, stream>>>(Wk, WB + 1048576, 262144);
  cvt_kernel<<<1024, 256, 0, stream>>>(Wv, WB + 2097152, 262144);

  gemm_qkv<<<dim3(8, 128, 3), 256, 0, stream>>>(EB, WB, Qb, Kb, Vb);
  transpose_v<<<dim3(64, 16, 4), 256, 0, stream>>>(Vb, VT);
  flash_attn<<<dim3(64, 4), 512, 0, stream>>>(Qb, Kb, VT, (float*)d_out);
}

// Round 3
// 697.869 us; speedup vs baseline: 1.9382x; 1.6489x over previous
//
#include <hip/hip_runtime.h>
#include <math.h>
#include <stdint.h>

#define SEQ 4096
#define DIM 1024
#define NB  4

typedef __attribute__((ext_vector_type(8))) __bf16 bf16x8;
typedef __attribute__((ext_vector_type(4))) float  f32x4;
typedef __attribute__((ext_vector_type(4))) float  floatx4;
typedef __attribute__((ext_vector_type(8))) unsigned short ushortx8;
typedef __attribute__((ext_vector_type(4))) unsigned short ushortx4;

__device__ __forceinline__ unsigned short f2bf(float f){
  union { float f; unsigned int u; } c; c.f = f;
  unsigned int u = c.u;
  return (unsigned short)((u + 0x7fffu + ((u >> 16) & 1u)) >> 16);
}

__device__ __forceinline__ f32x4 mfma16(bf16x8 a, bf16x8 b, f32x4 c){
  return __builtin_amdgcn_mfma_f32_16x16x32_bf16(a, b, c, 0, 0, 0);
}

__device__ __forceinline__ void g2l16(void* lds, const void* g){
  __builtin_amdgcn_global_load_lds(
      (const __attribute__((address_space(1))) unsigned int*)g,
      (__attribute__((address_space(3))) unsigned int*)lds, 16, 0, 0);
}

#define WAITVM4 asm volatile("s_waitcnt vmcnt(4)" ::: "memory")
#define WAITVM0 asm volatile("s_waitcnt vmcnt(0)" ::: "memory")

// ---------------- fp32 -> bf16 conversion ----------------
__global__ void cvt_kernel(const float* __restrict__ src,
                           unsigned short* __restrict__ dst, int n4){
  int i = blockIdx.x * blockDim.x + threadIdx.x;
  if (i >= n4) return;
  floatx4 v = *((const floatx4*)src + i);
  ushortx4 o;
  o[0] = f2bf(v[0]); o[1] = f2bf(v[1]); o[2] = f2bf(v[2]); o[3] = f2bf(v[3]);
  *((ushortx4*)dst + i) = o;
}

// ---------------- QKV projection GEMM (m97 structure) ----------------
__global__ __launch_bounds__(256, 2) void gemm_qkv(
    const unsigned short* __restrict__ E,
    const unsigned short* __restrict__ W3,
    unsigned short* __restrict__ Qd,
    unsigned short* __restrict__ Kd,
    unsigned short* __restrict__ Vd)
{
  __shared__ unsigned short As[128][64];
  __shared__ unsigned short Bs[128][64];

  const int t  = threadIdx.x;
  const int m0 = blockIdx.y * 128;
  const int n0 = blockIdx.x * 128;
  const unsigned short* W = W3 + (size_t)blockIdx.z * (DIM * (size_t)DIM);
  unsigned short* dst = blockIdx.z == 0 ? Qd : (blockIdx.z == 1 ? Kd : Vd);

  const int l  = t & 63;
  const int w  = t >> 6;
  const int lr = l & 15;
  const int lk = l >> 4;
  const int wr = (w >> 1) * 64;
  const int wc = (w & 1) * 64;

  f32x4 acc[4][4];
  #pragma unroll
  for (int i = 0; i < 4; ++i)
    #pragma unroll
    for (int j = 0; j < 4; ++j) acc[i][j] = (f32x4)0.0f;

  for (int kt = 0; kt < DIM / 64; ++kt){
    const int k0 = kt * 64;
    #pragma unroll
    for (int c = 0; c < 4; ++c){
      int id  = c * 256 + t;
      int row = id >> 3;
      int cb  = (id & 7) * 8;
      g2l16(&As[row][cb], E + (size_t)(m0 + row) * DIM + k0 + cb);
      g2l16(&Bs[row][cb], W + (size_t)(n0 + row) * DIM + k0 + cb);
    }
    asm volatile("s_waitcnt vmcnt(0)" ::: "memory");
    __syncthreads();
    #pragma unroll
    for (int ks = 0; ks < 2; ++ks){
      bf16x8 af[4], bfr[4];
      #pragma unroll
      for (int i = 0; i < 4; ++i){
        af[i]  = *(const bf16x8*)&As[wr + i*16 + lr][ks*32 + lk*8];
        bfr[i] = *(const bf16x8*)&Bs[wc + i*16 + lr][ks*32 + lk*8];
      }
      #pragma unroll
      for (int i = 0; i < 4; ++i)
        #pragma unroll
        for (int j = 0; j < 4; ++j)
          acc[i][j] = mfma16(af[i], bfr[j], acc[i][j]);
    }
    __syncthreads();
  }
  #pragma unroll
  for (int i = 0; i < 4; ++i)
    #pragma unroll
    for (int j = 0; j < 4; ++j)
      #pragma unroll
      for (int r = 0; r < 4; ++r){
        int row = wr + i*16 + lk*4 + r;
        int col = wc + j*16 + lr;
        dst[(size_t)(m0 + row) * DIM + n0 + col] = f2bf(acc[i][j][r]);
      }
}

// ---------------- V transpose ----------------
__global__ __launch_bounds__(256) void transpose_v(
    const unsigned short* __restrict__ V, unsigned short* __restrict__ VT)
{
  __shared__ unsigned short T[64][72];
  const int b  = blockIdx.z;
  const int s0 = blockIdx.x * 64;
  const int a0 = blockIdx.y * 64;
  const unsigned short* Vb = V + (size_t)b * SEQ * DIM;
  unsigned short* VTb = VT + (size_t)b * DIM * SEQ;
  const int t = threadIdx.x;
  const int r = t >> 3, cg = t & 7;
  #pragma unroll
  for (int p = 0; p < 2; ++p){
    int row = r + p * 32;
    ushortx8 v = *(const ushortx8*)(Vb + (size_t)(s0 + row) * DIM + a0 + cg*8);
    *(ushortx8*)&T[row][cg*8] = v;
  }
  __syncthreads();
  #pragma unroll
  for (int p = 0; p < 2; ++p){
    int ar = r + p * 32;
    ushortx8 o;
    #pragma unroll
    for (int j = 0; j < 8; ++j) o[j] = T[cg*8 + j][ar];
    *(ushortx8*)(VTb + (size_t)(a0 + ar) * SEQ + s0 + cg*8) = o;
  }
}

// ---------------- flash attention v3: LDS-staged K/V, counted vmcnt ----------------
// BQ=32, BK=64. 256 blocks x 512 threads. Pairing: tiles (127-pair, pair).
// Per KV iter: 8 chunk-phases (4x K-chunk 64x256, 4x V-chunk 256x64), each
// 32KB, ping-pong 2 buffers, staged 2-ahead via global_load_lds; softmax
// between K-phases and V-phases. All LDS XOR-swizzled (bit4 ^ row&7).

// stage chunk number cc (global stream idx within tile) if it exists
#define ISSUE_CHUNK(cc) do { \
  int _c = (cc); \
  if (_c < nj8){ \
    int _j = _c >> 3, _k = _c & 7; \
    char* _buf = cbuf + (size_t)(_c & 1) * 32768; \
    if (_k < 4){ \
      _Pragma("unroll") \
      for (int _u = 0; _u < 4; ++_u){ \
        int _s = _u * 512 + t; \
        int _r = _s >> 5; \
        int _o = ((_s & 31) * 16) ^ ((_r & 7) << 4); \
        g2l16(_buf + (size_t)_s * 16, \
              (const char*)(Kg + (size_t)(_j * 64 + _r) * DIM + _k * 256) + _o); \
      } \
    } else { \
      _Pragma("unroll") \
      for (int _u = 0; _u < 4; ++_u){ \
        int _s = _u * 512 + t; \
        int _r = _s >> 3; \
        int _o = ((_s & 7) * 16) ^ ((_r & 7) << 4); \
        g2l16(_buf + (size_t)_s * 16, \
              (const char*)(VTg + (size_t)((_k - 4) * 256 + _r) * SEQ + _j * 64) + _o); \
      } \
    } \
  } \
} while (0)

#define STAGE_Q(qtile) do { \
  const unsigned short* _Qg = Q + ((size_t)b * SEQ + (size_t)(qtile) * 32) * DIM; \
  _Pragma("unroll") \
  for (int _u = 0; _u < 8; ++_u){ \
    int _s = _u * 512 + t; \
    int _row = _s >> 7; \
    int _sB = ((_s & 127) * 16) ^ ((_row & 7) << 4); \
    g2l16(QsB + (size_t)_s * 16, (const char*)_Qg + (size_t)_row * 2048 + _sB); \
  } \
} while (0)

__global__ __launch_bounds__(512, 2) void flash_attn(
    const unsigned short* __restrict__ Q,
    const unsigned short* __restrict__ K,
    const unsigned short* __restrict__ VT,
    float* __restrict__ out)
{
  __shared__ char QsRaw[65536];     // Q tile 32x1024 bf16, swizzled
  __shared__ char cbufRaw[65536];   // 2 x 32KB chunk ping-pong
  __shared__ float Ss[32][68];
  __shared__ unsigned short Ps[32][72];
  __shared__ float mS[32], lS[32], aS[32];

  char* QsB  = QsRaw;
  char* cbuf = cbufRaw;

  const int fid  = blockIdx.x;
  const int xcd  = fid & 7;
  const int b    = xcd >> 1;                      // 2 XCDs per batch
  const int pair = (fid >> 3) + (xcd & 1) * 32;   // 0..63

  const int t  = threadIdx.x;
  const int w  = t >> 6;
  const int l  = t & 63;
  const int lr = l & 15;
  const int lk = l >> 4;
  const int lk16 = lk * 16;
  const int swz  = (lr & 7) << 4;

  const unsigned short* Kg  = K  + (size_t)b * SEQ * DIM;
  const unsigned short* VTg = VT + (size_t)b * DIM * SEQ;

  const float scale = 0.03125f;  // 1/sqrt(1024)

  // phase A roles (QK^T): S[32x64] = 2M x 4N frags
  const int mfa = w >> 2;
  const int nfa = w & 3;
  // phase C roles (PV): wave = (mfc rows, ng d-group); acc[dc*4+q]
  const int mfc = w & 1;
  const int ng  = w >> 1;

  const char* aRow = QsB + (size_t)(mfa * 16 + lr) * 2048;
  const size_t bRowOff = (size_t)(nfa * 16 + lr) * 512;
  const unsigned short* paP0 = &Ps[mfc * 16 + lr][lk * 8];
  const unsigned short* paP1 = &Ps[mfc * 16 + lr][32 + lk * 8];

  // tile 0 prologue: Q + chunks 0,1
  {
    const int qt0 = 127 - pair;
    STAGE_Q(qt0);
    const int nj8 = (qt0 / 2 + 1) * 8;
    ISSUE_CHUNK(0);
    ISSUE_CHUNK(1);
  }

  for (int tix = 0; tix < 2; ++tix){
    const int qt = tix ? pair : (127 - pair);
    const int nj = qt / 2 + 1;
    const int nj8 = nj * 8;

    if (tix) __syncthreads();               // epilogue lS reads done
    if (t < 32){ mS[t] = -INFINITY; lS[t] = 0.0f; }

    f32x4 acc[16];
    #pragma unroll
    for (int n = 0; n < 16; ++n) acc[n] = (f32x4)0.0f;

    int c = 0;                               // chunk stream counter
    for (int j = 0; j < nj; ++j){
      f32x4 sA0 = (f32x4)0.0f, sA1 = (f32x4)0.0f;

      // ---- 4 K-chunk phases: S += Q[:,chunk] K[:,chunk]^T ----
      #pragma unroll
      for (int dc = 0; dc < 4; ++dc){
        if (c + 1 < nj8) { WAITVM4; } else { WAITVM0; }
        __syncthreads();
        {
          const char* bB = cbuf + (size_t)(dc & 1) * 32768 + bRowOff;
          bf16x8 qa[8], kb[8];
          #pragma unroll
          for (int ks = 0; ks < 8; ++ks){
            qa[ks] = *(const bf16x8*)(aRow + ((dc * 512 + ks * 64 + lk16) ^ swz));
            kb[ks] = *(const bf16x8*)(bB + ((ks * 64 + lk16) ^ swz));
          }
          __builtin_amdgcn_s_setprio(1);
          #pragma unroll
          for (int ks = 0; ks < 8; ks += 2){
            sA0 = mfma16(qa[ks],     kb[ks],     sA0);
            sA1 = mfma16(qa[ks + 1], kb[ks + 1], sA1);
          }
          __builtin_amdgcn_s_setprio(0);
        }
        if (dc == 3){
          f32x4 sv = sA0 + sA1;
          #pragma unroll
          for (int r = 0; r < 4; ++r)
            Ss[mfa * 16 + lk * 4 + r][nfa * 16 + lr] = sv[r];
        }
        __syncthreads();
        ISSUE_CHUNK(c + 2);
        ++c;
      }

      // ---- softmax over this 32x64 tile (V1 loads in flight) ----
      {
        const int row = t >> 4;
        const int cg  = t & 15;
        f32x4 v0 = *(const f32x4*)&Ss[row][cg * 4];
        const int grow = qt * 32 + row;
        const int gc0  = j * 64 + cg * 4;
        float svv[4];
        #pragma unroll
        for (int i2 = 0; i2 < 4; ++i2)
          svv[i2] = (gc0 + i2 > grow) ? -INFINITY : v0[i2] * scale;
        float mx = fmaxf(fmaxf(svv[0], svv[1]), fmaxf(svv[2], svv[3]));
        #pragma unroll
        for (int d = 1; d < 16; d <<= 1) mx = fmaxf(mx, __shfl_xor(mx, d, 64));
        float mprev = mS[row];
        float mnew  = fmaxf(mprev, mx);
        float alpha = __expf(mprev - mnew);
        float sum = 0.f;
        ushortx4 pb;
        #pragma unroll
        for (int i2 = 0; i2 < 4; ++i2){
          float p = __expf(svv[i2] - mnew);
          sum += p;
          pb[i2] = f2bf(p);
        }
        #pragma unroll
        for (int d = 1; d < 16; d <<= 1) sum += __shfl_xor(sum, d, 64);
        if (cg == 0){
          mS[row] = mnew;
          lS[row] = lS[row] * alpha + sum;
          aS[row] = alpha;
        }
        *(ushortx4*)&Ps[row][cg * 4] = pb;
      }
      // no barrier here: the V0 phase entry barrier publishes Ps/aS

      // ---- 4 V-chunk phases: O[:,chunk] = O*alpha + P V[chunk] ----
      #pragma unroll
      for (int dc = 0; dc < 4; ++dc){
        if (c + 1 < nj8) { WAITVM4; } else { WAITVM0; }
        __syncthreads();
        if (dc == 0){
          float al[4];
          #pragma unroll
          for (int r = 0; r < 4; ++r) al[r] = aS[mfc * 16 + lk * 4 + r];
          #pragma unroll
          for (int n = 0; n < 16; ++n)
            #pragma unroll
            for (int r = 0; r < 4; ++r) acc[n][r] *= al[r];
        }
        {
          bf16x8 pa0 = *(const bf16x8*)paP0;
          bf16x8 pa1 = *(const bf16x8*)paP1;
          const char* vB = cbuf + (size_t)(dc & 1) * 32768;
          __builtin_amdgcn_s_setprio(1);
          #pragma unroll
          for (int q = 0; q < 4; ++q){
            const int dl = (ng * 4 + q) * 16 + lr;
            const char* vr = vB + (size_t)dl * 128;
            bf16x8 vb0 = *(const bf16x8*)(vr + ((lk16) ^ swz));
            bf16x8 vb1 = *(const bf16x8*)(vr + ((64 + lk16) ^ swz));
            acc[dc * 4 + q] = mfma16(pa0, vb0, acc[dc * 4 + q]);
            acc[dc * 4 + q] = mfma16(pa1, vb1, acc[dc * 4 + q]);
          }
          __builtin_amdgcn_s_setprio(0);
        }
        __syncthreads();
        ISSUE_CHUNK(c + 2);
        ++c;
      }
    }

    // prefetch next tile's Q + chunks 0,1 (overlaps epilogue)
    if (tix == 0){
      const int qt1 = pair;
      STAGE_Q(qt1);
      const int nj8 = (qt1 / 2 + 1) * 8;
      ISSUE_CHUNK(0);
      ISSUE_CHUNK(1);
    }

    // ---- epilogue: O / l ----
    {
      float* ob = out + ((size_t)b * SEQ + (size_t)qt * 32 + mfc * 16) * DIM;
      #pragma unroll
      for (int r = 0; r < 4; ++r){
        int rl = lk * 4 + r;
        float inv = 1.0f / lS[mfc * 16 + rl];
        #pragma unroll
        for (int dc = 0; dc < 4; ++dc)
          #pragma unroll
          for (int q = 0; q < 4; ++q){
            int col = dc * 256 + (ng * 4 + q) * 16 + lr;
            ob[(size_t)rl * DIM + col] = acc[dc * 4 + q][r] * inv;
          }
      }
    }
  }
}

// ---------------- launch ----------------
extern "C" void kernel_launch(void* const* d_in, const int* in_sizes, int n_in,
                              void* d_out, int out_size, void* d_ws, size_t ws_size,
                              hipStream_t stream)
{
  (void)in_sizes; (void)n_in; (void)out_size; (void)ws_size;
  const float* emb = (const float*)d_in[0];
  const float* Wq  = (const float*)d_in[1];
  const float* Wk  = (const float*)d_in[2];
  const float* Wv  = (const float*)d_in[3];

  char* ws = (char*)d_ws;
  unsigned short* EB = (unsigned short*)ws;                    // 32MB (later reused as VT)
  unsigned short* WB = (unsigned short*)(ws + 33554432);       // 6MB
  unsigned short* Qb = (unsigned short*)(ws + 39845888);       // 32MB
  unsigned short* Kb = (unsigned short*)(ws + 73400320);       // 32MB
  unsigned short* Vb = (unsigned short*)d_out;                 // V scratch in out buffer
  unsigned short* VT = EB;

  cvt_kernel<<<16384, 256, 0, stream>>>(emb, EB, 4194304);
  cvt_kernel<<<1024, 256, 0, stream>>>(Wq, WB,           262144);
  cvt_kernel<<<1024, 256, 0, stream>>>(Wk, WB + 1048576, 262144);
  cvt_kernel<<<1024, 256, 0, stream>>>(Wv, WB + 2097152, 262144);

  gemm_qkv<<<dim3(8, 128, 3), 256, 0, stream>>>(EB, WB, Qb, Kb, Vb);
  transpose_v<<<dim3(64, 16, 4), 256, 0, stream>>>(Vb, VT);
  flash_attn<<<256, 512, 0, stream>>>(Qb, Kb, VT, (float*)d_out);
}